// Round 1
// baseline (753.773 us; speedup 1.0000x reference)
//
#include <hip/hip_runtime.h>

// ---------------------------------------------------------------------------
// Sparse UNet forward — round 11: output-stationary binned gather conv for
// the coarse level (down conv + conv2).
//   - bins rulebook by (128-row output range, tap); block owns a 128x64 f32
//     LDS accumulator tile; ds_add_f32 scatter (stride 66 -> <=2-way conflict)
//   - center tap folded in (identity gather) -> conv_center dispatch dropped
//   - single non-atomic output write + fused BN stats -> bn_stats dropped
//   - Cf zero-fill dropped (every row written exactly once)
// Fine-level convs / deconv unchanged from r10.
// ---------------------------------------------------------------------------

#define EPS 1e-4f

typedef __attribute__((ext_vector_type(8))) short short8;   // 8 x bf16
typedef __attribute__((ext_vector_type(4))) float f32x4;

__device__ __forceinline__ unsigned short f2bf(float f) {
    union { float f; unsigned int u; } v; v.f = f;
    unsigned int r = v.u + 0x7fffu + ((v.u >> 16) & 1u);   // RNE
    return (unsigned short)(r >> 16);
}

__global__ void zero_kernel(float* p, long n) {
    long i = (long)blockIdx.x * 256 + threadIdx.x;
    if (i < n) p[i] = 0.f;
}

// Per-channel sum / sumsq -> stats[0:C], stats[C:2C] (atomic accumulate).
template <int C>
__global__ __launch_bounds__(256) void bn_stats(const float* __restrict__ x,
                                                int rows, int stride,
                                                float* __restrict__ stats) {
    const int tid = threadIdx.x;
    const int c = tid & (C - 1);
    const int g = tid / C;
    const int GR = 256 / C;
    float s = 0.f, s2 = 0.f;
    for (int r = blockIdx.x * GR + g; r < rows; r += gridDim.x * GR) {
        float v = x[(size_t)r * stride + c];
        s += v; s2 += v * v;
    }
    __shared__ float sh[2][256];
    sh[0][tid] = s; sh[1][tid] = s2;
    __syncthreads();
    for (int off = 128; off >= C; off >>= 1) {
        if (tid < off) { sh[0][tid] += sh[0][tid + off]; sh[1][tid] += sh[1][tid + off]; }
        __syncthreads();
    }
    if (tid < C) {
        atomicAdd(&stats[c], sh[0][tid]);
        atomicAdd(&stats[C + c], sh[1][tid]);
    }
}

// BN finalize + ReLU -> bf16. Output packed (rows+1) x C, sentinel row zeroed.
template <int C, int CSPLIT>
__global__ __launch_bounds__(256) void bn_norm_relu_bf16(
    const float* __restrict__ x, int rows, int stride,
    const float* __restrict__ stA, const float* __restrict__ stB,
    const float* __restrict__ gamma, const float* __restrict__ beta,
    unsigned short* __restrict__ y) {
    constexpr int TPR = C / 8;
    int gid = blockIdx.x * 256 + threadIdx.x;
    int r = gid / TPR, t = gid % TPR;
    if (r > rows) return;
    short8 o8;
    if (r == rows) {
        for (int j = 0; j < 8; ++j) o8[j] = 0;
    } else {
        const float inv_n = 1.0f / (float)rows;
        const float* xr = x + (size_t)r * stride + t * 8;
        float4 v0 = *(const float4*)(xr);
        float4 v1 = *(const float4*)(xr + 4);
        float vv[8] = {v0.x, v0.y, v0.z, v0.w, v1.x, v1.y, v1.z, v1.w};
#pragma unroll
        for (int j = 0; j < 8; ++j) {
            int c = t * 8 + j;
            const float* st = (c < CSPLIT) ? stA : stB;
            int cc = (c < CSPLIT) ? c : c - CSPLIT;
            int cs = (c < CSPLIT) ? CSPLIT : (C - CSPLIT);
            float mu = st[cc] * inv_n;
            float var = st[cs + cc] * inv_n - mu * mu;
            float sc = gamma[c] * rsqrtf(var + EPS);
            float shf = beta[c] - mu * sc;
            float ov = fmaxf(0.f, fmaf(vv[j], sc, shf));
            o8[j] = (short)f2bf(ov);
        }
    }
    *(short8*)(y + (size_t)r * C + t * 8) = o8;
}

// One dispatch: all 5 weight transposes/casts f32 [K][CIN][COUT] -> bf16
// [K][COUT][CIN].
__device__ __forceinline__ void wt_seg(const float* W, unsigned short* WT,
                                       int id, int CIN, int COUT) {
    int r = id % (CIN * COUT);
    int t = id / (CIN * COUT);
    int co = r / CIN;
    int ci = r % CIN;
    WT[id] = f2bf(W[(size_t)t * CIN * COUT + ci * COUT + co]);
}
__global__ __launch_bounds__(256) void wt_transpose_all(
    const float* w1, const float* wd, const float* w2, const float* w3,
    const float* wu, unsigned short* o1, unsigned short* od,
    unsigned short* o2, unsigned short* o3, unsigned short* ou) {
    int id = blockIdx.x * 256 + threadIdx.x;
    // segment sizes: 27648, 16384, 110592, 55296, 16384 (total 226304)
    if (id < 27648) { wt_seg(w1, o1, id, 32, 32); return; }
    id -= 27648;
    if (id < 16384) { wt_seg(wd, od, id, 32, 64); return; }
    id -= 16384;
    if (id < 110592) { wt_seg(w2, o2, id, 64, 64); return; }
    id -= 110592;
    if (id < 55296) { wt_seg(w3, o3, id, 64, 32); return; }
    id -= 55296;
    if (id < 16384) { wt_seg(wu, ou, id, 64, 32); return; }
}

// ---- rulebook builders -----------------------------------------------------
// Fine-level compacted per-tap rulebook (r9, verified fast).
__global__ __launch_bounds__(256) void build_rb_tap(
    const int* __restrict__ nbr, int rows, int P, int cap, int kskip,
    int2* __restrict__ rb, int* __restrict__ cnt) {
    const int tap = blockIdx.y;
    const int k = tap + (tap >= kskip ? 1 : 0);
    const int* nk = nbr + (size_t)k * rows;
    const int lane = threadIdx.x & 63;
    const int wave = threadIdx.x >> 6;
    const long wbase = (long)blockIdx.x * 1024 + wave * 256;

    unsigned long long masks[4];
    int vs[4], tot[4], wtotal = 0;
#pragma unroll
    for (int c = 0; c < 4; ++c) {
        long m = wbase + c * 64 + lane;
        int v = (m < rows) ? nk[m] : P;
        vs[c] = v;
        masks[c] = __ballot(v != P);
        tot[c] = __popcll(masks[c]);
        wtotal += tot[c];
    }
    __shared__ int sh[5];
    if (lane == 0) sh[wave] = wtotal;
    __syncthreads();
    if (threadIdx.x == 0) {
        int t = sh[0] + sh[1] + sh[2] + sh[3];
        sh[4] = t ? atomicAdd(&cnt[tap * 32], t) : 0;
    }
    __syncthreads();
    int base = sh[4];
    for (int w = 0; w < wave; ++w) base += sh[w];
#pragma unroll
    for (int c = 0; c < 4; ++c) {
        if (vs[c] != P) {
            int rank = __popcll(masks[c] & ((1ull << lane) - 1ull));
            int j = base + rank;
            if (j < cap)
                rb[(size_t)tap * cap + j] = make_int2((int)(wbase + c * 64 + lane), vs[c]);
        }
        base += tot[c];
    }
}

__global__ __launch_bounds__(256) void build_rb_up(
    const int* __restrict__ up_cidx, const int* __restrict__ up_k,
    int rows, int cap, int2* __restrict__ rb, int* __restrict__ cnt) {
    const int s = blockIdx.y;
    const int lane = threadIdx.x & 63;
    const int wave = threadIdx.x >> 6;
    const long wbase = (long)blockIdx.x * 1024 + wave * 256;

    unsigned long long masks[4];
    int cs[4], ok[4], tot[4], wtotal = 0;
#pragma unroll
    for (int c = 0; c < 4; ++c) {
        long i = wbase + c * 64 + lane;
        int seg = (i < rows) ? up_k[i] : -1;
        cs[c] = (i < rows) ? up_cidx[i] : 0;
        ok[c] = (seg == s);
        masks[c] = __ballot(ok[c]);
        tot[c] = __popcll(masks[c]);
        wtotal += tot[c];
    }
    __shared__ int sh[5];
    if (lane == 0) sh[wave] = wtotal;
    __syncthreads();
    if (threadIdx.x == 0) {
        int t = sh[0] + sh[1] + sh[2] + sh[3];
        sh[4] = t ? atomicAdd(&cnt[s * 32], t) : 0;
    }
    __syncthreads();
    int base = sh[4];
    for (int w = 0; w < wave; ++w) base += sh[w];
#pragma unroll
    for (int c = 0; c < 4; ++c) {
        if (ok[c]) {
            int rank = __popcll(masks[c] & ((1ull << lane) - 1ull));
            int j = base + rank;
            if (j < cap)
                rb[(size_t)s * cap + j] = make_int2((int)(wbase + c * 64 + lane), cs[c]);
        }
        base += tot[c];
    }
}

// Binned rulebook: bins[(m>>7)][tap][cap] of (local_row, in_row).
__global__ __launch_bounds__(256) void build_bins(
    const int* __restrict__ nbr, int rows, int P, int ntap, int kskip, int cap,
    int2* __restrict__ bins, int* __restrict__ bcnt) {
    int m = blockIdx.x * 256 + threadIdx.x;
    if (m >= rows) return;
    int tt = blockIdx.y;
    int k = tt + (tt >= kskip ? 1 : 0);
    int v = nbr[(size_t)k * rows + m];
    if (v == P) return;
    int bin = m >> 7;
    int pos = atomicAdd(&bcnt[(size_t)bin * ntap + tt], 1);
    if (pos < cap)
        bins[((size_t)bin * ntap + tt) * cap + pos] = make_int2(m & 127, v);
}

// ---- conv kernels ----------------------------------------------------------

// Dense center-tap GEMM (identity gather): out[m] = fpad[m] @ Wk, plain write.
template <int CIN, int COT>
__global__ __launch_bounds__(256) void conv_center(
    const unsigned short* __restrict__ fpad,
    const unsigned short* __restrict__ Wk,
    float* __restrict__ out, int rows, int P, int out_stride) {
    constexpr int N_SUB = COT / 16;
    constexpr int K_SUB = CIN / 32;
    const int tid = threadIdx.x;
    const int wave = tid >> 6;
    const int lane = tid & 63;
    const int q = lane >> 4;
    const int l15 = lane & 15;
    const int m0 = blockIdx.x * 128 + wave * 32;

    f32x4 acc[2][N_SUB];
#pragma unroll
    for (int mt = 0; mt < 2; ++mt)
#pragma unroll
        for (int nt = 0; nt < N_SUB; ++nt) acc[mt][nt] = (f32x4){0.f, 0.f, 0.f, 0.f};

    short8 a[2][K_SUB], b[N_SUB][K_SUB];
#pragma unroll
    for (int mt = 0; mt < 2; ++mt) {
        int m = m0 + mt * 16 + l15;
        int src = (m < rows) ? m : P;
#pragma unroll
        for (int kf = 0; kf < K_SUB; ++kf)
            a[mt][kf] = *(const short8*)(fpad + (size_t)src * CIN + kf * 32 + q * 8);
    }
#pragma unroll
    for (int nt = 0; nt < N_SUB; ++nt)
#pragma unroll
        for (int kf = 0; kf < K_SUB; ++kf)
            b[nt][kf] = *(const short8*)(Wk + (size_t)(nt * 16 + l15) * CIN + kf * 32 + q * 8);
#pragma unroll
    for (int mt = 0; mt < 2; ++mt)
#pragma unroll
        for (int nt = 0; nt < N_SUB; ++nt)
#pragma unroll
            for (int kf = 0; kf < K_SUB; ++kf)
                acc[mt][nt] = __builtin_amdgcn_mfma_f32_16x16x32_bf16(
                    a[mt][kf], b[nt][kf], acc[mt][nt], 0, 0, 0);
#pragma unroll
    for (int mt = 0; mt < 2; ++mt)
#pragma unroll
        for (int i = 0; i < 4; ++i) {
            int row = m0 + mt * 16 + q * 4 + i;
            if (row < rows) {
#pragma unroll
                for (int nt = 0; nt < N_SUB; ++nt)
                    out[(size_t)row * out_stride + nt * 16 + l15] = acc[mt][nt][i];
            }
        }
}

// Sparse-tap gather-GEMM over compacted rulebook tiles (fine level + deconv).
template <int CIN, int COT, bool ATOMIC>
__global__ __launch_bounds__(256) void conv_sparse(
    const unsigned short* __restrict__ fpad,
    const int2* __restrict__ rb,
    const int* __restrict__ cnt,
    const unsigned short* __restrict__ WT,
    float* __restrict__ out,
    float* __restrict__ stats,
    int cap, int kskip, int P, int out_stride) {
    constexpr int N_SUB = COT / 16;
    constexpr int K_SUB = CIN / 32;
    const int tap = blockIdx.y;
    int n = cnt[tap * 32];
    n = n < cap ? n : cap;
    const int nbx = gridDim.x;
    const int step = (nbx >> 3) | 1;
    const int px = (int)((blockIdx.x + (unsigned)tap * step) % (unsigned)nbx);
    const int base0 = px * 128;
    if (base0 >= n) return;
    const int k = tap + (tap >= kskip ? 1 : 0);
    const int tid = threadIdx.x;
    const int wave = tid >> 6;
    const int lane = tid & 63;
    const int q = lane >> 4;
    const int l15 = lane & 15;
    const int base = base0 + wave * 32;
    const int2* seg = rb + (size_t)tap * cap;

    f32x4 acc[2][N_SUB];
#pragma unroll
    for (int mt = 0; mt < 2; ++mt)
#pragma unroll
        for (int nt = 0; nt < N_SUB; ++nt) acc[mt][nt] = (f32x4){0.f, 0.f, 0.f, 0.f};

    short8 a[2][K_SUB], b[N_SUB][K_SUB];
#pragma unroll
    for (int mt = 0; mt < 2; ++mt) {
        int j = base + mt * 16 + l15;
        int src = (j < n) ? seg[j].y : P;
#pragma unroll
        for (int kf = 0; kf < K_SUB; ++kf)
            a[mt][kf] = *(const short8*)(fpad + (size_t)src * CIN + kf * 32 + q * 8);
    }
    const unsigned short* Wk = WT + (size_t)k * COT * CIN;
#pragma unroll
    for (int nt = 0; nt < N_SUB; ++nt)
#pragma unroll
        for (int kf = 0; kf < K_SUB; ++kf)
            b[nt][kf] = *(const short8*)(Wk + (size_t)(nt * 16 + l15) * CIN + kf * 32 + q * 8);
#pragma unroll
    for (int mt = 0; mt < 2; ++mt)
#pragma unroll
        for (int nt = 0; nt < N_SUB; ++nt)
#pragma unroll
            for (int kf = 0; kf < K_SUB; ++kf)
                acc[mt][nt] = __builtin_amdgcn_mfma_f32_16x16x32_bf16(
                    a[mt][kf], b[nt][kf], acc[mt][nt], 0, 0, 0);

#pragma unroll
    for (int mt = 0; mt < 2; ++mt)
#pragma unroll
        for (int i = 0; i < 4; ++i) {
            int j = base + mt * 16 + q * 4 + i;
            if (j < n) {
                int row = seg[j].x;
                float* o = out + (size_t)row * out_stride + l15;
#pragma unroll
                for (int nt = 0; nt < N_SUB; ++nt) {
                    if (ATOMIC) atomicAdd(o + nt * 16, acc[mt][nt][i]);
                    else        o[nt * 16] = acc[mt][nt][i];
                }
            }
        }

    // Fused BN stats (final-value writes only): OOB lanes hold acc==0.
    if (!ATOMIC && stats) {
        __shared__ float ssum[COT], ssq[COT];
        for (int i = tid; i < 2 * COT; i += 256)
            (i < COT ? ssum[i] : ssq[i - COT]) = 0.f;
        __syncthreads();
#pragma unroll
        for (int nt = 0; nt < N_SUB; ++nt) {
            float s = 0.f, s2 = 0.f;
#pragma unroll
            for (int mt = 0; mt < 2; ++mt)
#pragma unroll
                for (int i = 0; i < 4; ++i) {
                    float v = acc[mt][nt][i];
                    s += v; s2 += v * v;
                }
            s += __shfl_xor(s, 16);  s += __shfl_xor(s, 32);
            s2 += __shfl_xor(s2, 16); s2 += __shfl_xor(s2, 32);
            if (q == 0) {
                atomicAdd(&ssum[nt * 16 + l15], s);
                atomicAdd(&ssq[nt * 16 + l15], s2);
            }
        }
        __syncthreads();
        if (tid < COT) {
            atomicAdd(&stats[tid], ssum[tid]);
            atomicAdd(&stats[COT + tid], ssq[tid]);
        }
    }
}

// Output-stationary binned gather conv: one block per 128-row output range.
// Waves loop over taps; gather-GEMM 32-entry groups; ds_add_f32 into a
// 128 x COT f32 LDS tile (stride COT+2 -> <=2-way bank conflict); single
// non-atomic global write + fused BN stats in the epilogue.
template <int CIN, int COT, int NTAP, bool CENTER>
__global__ __launch_bounds__(256) void conv_binned(
    const unsigned short* __restrict__ fpad,
    const int2* __restrict__ bins,
    const int* __restrict__ bcnt,
    const unsigned short* __restrict__ WT,
    float* __restrict__ out,
    float* __restrict__ stats,
    int rows_out, int P, int out_stride, int cap) {
    constexpr int N_SUB = COT / 16;
    constexpr int K_SUB = CIN / 32;
    constexpr int LST = COT + 2;
    __shared__ float lacc[128 * LST];
    const int tid = threadIdx.x;
    const int wave = tid >> 6;
    const int lane = tid & 63;
    const int q = lane >> 4;
    const int l15 = lane & 15;
    const int base = blockIdx.x * 128;

    for (int i = tid; i < 128 * LST; i += 256) lacc[i] = 0.f;
    __syncthreads();

    short8 b[N_SUB][K_SUB];

    auto do_group = [&](const int2* seg, int j0, int n, int roff, bool center) {
        short8 a[2][K_SUB];
#pragma unroll
        for (int mt = 0; mt < 2; ++mt) {
            int e = j0 + mt * 16 + l15;
            int src = P;
            if (e < n) src = center ? (base + roff + e) : seg[e].y;
#pragma unroll
            for (int kf = 0; kf < K_SUB; ++kf)
                a[mt][kf] = *(const short8*)(fpad + (size_t)src * CIN + kf * 32 + q * 8);
        }
        f32x4 acc[2][N_SUB];
#pragma unroll
        for (int mt = 0; mt < 2; ++mt)
#pragma unroll
            for (int nt = 0; nt < N_SUB; ++nt) acc[mt][nt] = (f32x4){0.f, 0.f, 0.f, 0.f};
#pragma unroll
        for (int mt = 0; mt < 2; ++mt)
#pragma unroll
            for (int nt = 0; nt < N_SUB; ++nt)
#pragma unroll
                for (int kf = 0; kf < K_SUB; ++kf)
                    acc[mt][nt] = __builtin_amdgcn_mfma_f32_16x16x32_bf16(
                        a[mt][kf], b[nt][kf], acc[mt][nt], 0, 0, 0);
#pragma unroll
        for (int mt = 0; mt < 2; ++mt)
#pragma unroll
            for (int i = 0; i < 4; ++i) {
                int e = j0 + mt * 16 + q * 4 + i;
                if (e < n) {
                    int lr = center ? (roff + e) : seg[e].x;
                    float* dst = &lacc[lr * LST + l15];
#pragma unroll
                    for (int nt = 0; nt < N_SUB; ++nt)
                        atomicAdd(dst + nt * 16, acc[mt][nt][i]);
                }
            }
    };

    if (CENTER) {
        const unsigned short* Wk = WT + (size_t)13 * COT * CIN;
#pragma unroll
        for (int nt = 0; nt < N_SUB; ++nt)
#pragma unroll
            for (int kf = 0; kf < K_SUB; ++kf)
                b[nt][kf] = *(const short8*)(Wk + (size_t)(nt * 16 + l15) * CIN + kf * 32 + q * 8);
        int n = rows_out - base - wave * 32;
        n = n < 0 ? 0 : (n > 32 ? 32 : n);
        if (n > 0) do_group(nullptr, 0, n, wave * 32, true);
    }
    for (int tt = wave; tt < NTAP; tt += 4) {
        int n = bcnt[(size_t)blockIdx.x * NTAP + tt];
        n = n < cap ? n : cap;
        if (n == 0) continue;
        const int k = CENTER ? (tt + (tt >= 13 ? 1 : 0)) : tt;
        const unsigned short* Wk = WT + (size_t)k * COT * CIN;
#pragma unroll
        for (int nt = 0; nt < N_SUB; ++nt)
#pragma unroll
            for (int kf = 0; kf < K_SUB; ++kf)
                b[nt][kf] = *(const short8*)(Wk + (size_t)(nt * 16 + l15) * CIN + kf * 32 + q * 8);
        const int2* seg = bins + ((size_t)blockIdx.x * NTAP + tt) * cap;
        for (int j0 = 0; j0 < n; j0 += 32) do_group(seg, j0, n, 0, false);
    }
    __syncthreads();

    // Epilogue: single write per row + fused BN stats.
    constexpr int CG = COT / 4;          // col groups of 4 floats
    constexpr int RSTEP = 256 / CG;
    const int cg = tid & (CG - 1);
    const int r0 = tid / CG;
    float s[4] = {0.f, 0.f, 0.f, 0.f}, s2[4] = {0.f, 0.f, 0.f, 0.f};
    for (int r = r0; r < 128; r += RSTEP) {
        int row = base + r;
        if (row >= rows_out) break;
        float v[4];
#pragma unroll
        for (int j = 0; j < 4; ++j) {
            v[j] = lacc[r * LST + cg * 4 + j];
            s[j] += v[j]; s2[j] += v[j] * v[j];
        }
        *(float4*)(out + (size_t)row * out_stride + cg * 4) =
            make_float4(v[0], v[1], v[2], v[3]);
    }
#pragma unroll
    for (int j = 0; j < 4; ++j) {
        s[j]  += __shfl_xor(s[j], 16);  s[j]  += __shfl_xor(s[j], 32);
        s2[j] += __shfl_xor(s2[j], 16); s2[j] += __shfl_xor(s2[j], 32);
    }
    __syncthreads();
    if (tid < 2 * COT) lacc[tid] = 0.f;
    __syncthreads();
    if ((lane >> 4) == 0) {
#pragma unroll
        for (int j = 0; j < 4; ++j) {
            atomicAdd(&lacc[cg * 4 + j], s[j]);
            atomicAdd(&lacc[COT + cg * 4 + j], s2[j]);
        }
    }
    __syncthreads();
    if (tid < 2 * COT) atomicAdd(&stats[tid], lacc[tid]);
}

static inline int ceil_div(long a, long b) { return (int)((a + b - 1) / b); }

extern "C" void kernel_launch(void* const* d_in, const int* in_sizes, int n_in,
                              void* d_out, int out_size, void* d_ws, size_t ws_size,
                              hipStream_t stream) {
    const float* feat   = (const float*)d_in[0];
    const float* w_sub1 = (const float*)d_in[1];
    const float* w_down = (const float*)d_in[2];
    const float* w_sub2 = (const float*)d_in[3];
    const float* w_up   = (const float*)d_in[4];
    const float* w_sub3 = (const float*)d_in[5];
    const float* g1 = (const float*)d_in[6],  *b1 = (const float*)d_in[7];
    const float* g2 = (const float*)d_in[8],  *b2 = (const float*)d_in[9];
    const float* g3 = (const float*)d_in[10], *b3 = (const float*)d_in[11];
    const float* g4 = (const float*)d_in[12], *b4 = (const float*)d_in[13];
    const float* g5 = (const float*)d_in[14], *b5 = (const float*)d_in[15];
    const int* nbr_fine   = (const int*)d_in[16];
    const int* nbr_coarse = (const int*)d_in[17];
    const int* down_idx   = (const int*)d_in[18];
    const int* up_cidx    = (const int*)d_in[19];
    const int* up_k       = (const int*)d_in[20];

    const int N = in_sizes[0] / 32;
    const int M = in_sizes[17] / 27;
    const size_t maxr = (size_t)((N > M ? N : M) + 1);
    const int ranges = (M + 127) / 128;   // coarse-level 128-row output ranges

    // rulebook caps
    const int cap_f = 8192;      // fine per-tap (~2.6k expected)
    const int cap_u = 32768;     // up segments (~25.6k expected)
    const int bcap_c = 48;       // coarse bin: Binom(128,0.092) mean 11.7 (+11 sigma)
    const int bcap_d = 64;       // down bin:   Binom(128,0.132) mean 16.9 (+12 sigma)

    char* ws = (char*)d_ws;
    size_t off = 0;
    auto alloc = [&](size_t bytes) { void* p = ws + off; off += (bytes + 255) & ~(size_t)255; return p; };
    float* stats = (float*)alloc(768 * sizeof(float));
    int*   cnts  = (int*)alloc(4096 * sizeof(int));              // fine/up: 32 ints/tap
    int*   bcnt_c = (int*)alloc((size_t)ranges * 26 * sizeof(int));
    int*   bcnt_d = (int*)alloc((size_t)ranges * 8 * sizeof(int));
    const size_t zero_words = (off) / 4;                          // stats..bcnt_d contiguous
    float* D  = (float*)alloc((size_t)N * 64 * sizeof(float));    // concat buf [skip|up]
    float* Cf = (float*)alloc((size_t)M * 64 * sizeof(float));    // coarse f32 temp
    unsigned short* FA = (unsigned short*)alloc(maxr * 64 * 2);
    unsigned short* FB = (unsigned short*)alloc(maxr * 64 * 2);
    int2* rb_fine = (int2*)alloc((size_t)26 * cap_f * sizeof(int2));
    int2* rb_up   = (int2*)alloc((size_t)8 * cap_u * sizeof(int2));
    int2* bins_c  = (int2*)alloc((size_t)ranges * 26 * bcap_c * sizeof(int2));
    int2* bins_d  = (int2*)alloc((size_t)ranges * 8 * bcap_d * sizeof(int2));
    unsigned short* w1t = (unsigned short*)alloc(27 * 32 * 32 * 2);
    unsigned short* wdt = (unsigned short*)alloc(8 * 32 * 64 * 2);
    unsigned short* w2t = (unsigned short*)alloc(27 * 64 * 64 * 2);
    unsigned short* w3t = (unsigned short*)alloc(27 * 64 * 32 * 2);
    unsigned short* wupT = (unsigned short*)alloc(8 * 64 * 32 * 2);

    float* st0 = stats + 0 * 128;
    float* st1 = stats + 1 * 128;   // conv1 out (32 ch)
    float* st2 = stats + 2 * 128;   // down out (64 ch, fused in conv_binned)
    float* st3 = stats + 3 * 128;   // conv2 out (64 ch, fused in conv_binned)
    float* st4 = stats + 4 * 128;   // deconv out (32 ch, fused in deconv)
    int* cnt_fine = cnts;            // 26 taps * 32 stride
    int* cnt_up   = cnts + 26 * 32;

    // ---- setup ----
    zero_kernel<<<ceil_div((long)zero_words, 256), 256, 0, stream>>>(stats, (long)zero_words);
    wt_transpose_all<<<ceil_div(226304, 256), 256, 0, stream>>>(
        w_sub1, w_down, w_sub2, w_sub3, w_up, w1t, wdt, w2t, w3t, wupT);
    build_rb_tap<<<dim3(ceil_div(N, 1024), 26), 256, 0, stream>>>(
        nbr_fine, N, N, cap_f, 13, rb_fine, cnt_fine);
    build_rb_up<<<dim3(ceil_div(N, 1024), 8), 256, 0, stream>>>(
        up_cidx, up_k, N, cap_u, rb_up, cnt_up);
    build_bins<<<dim3(ceil_div(M, 256), 26), 256, 0, stream>>>(
        nbr_coarse, M, M, 26, 13, bcap_c, bins_c, bcnt_c);
    build_bins<<<dim3(ceil_div(M, 256), 8), 256, 0, stream>>>(
        down_idx, M, N, 8, 99, bcap_d, bins_d, bcnt_d);

    // 1) BN0+ReLU(feat) -> FA [(N+1)x32 bf16]
    bn_stats<32><<<256, 256, 0, stream>>>(feat, N, 32, st0);
    bn_norm_relu_bf16<32, 32><<<ceil_div((long)(N + 1) * 4, 256), 256, 0, stream>>>(
        feat, N, 32, st0, st0, g1, b1, FA);
    // 2) conv1 (27, 32->32): center write + sparse atomics -> D[:,0:32]
    conv_center<32, 32><<<ceil_div(N, 128), 256, 0, stream>>>(
        FA, w1t + 13 * 32 * 32, D, N, N, 64);
    conv_sparse<32, 32, true><<<dim3(cap_f / 128, 26), 256, 0, stream>>>(
        FA, rb_fine, cnt_fine, w1t, D, nullptr, cap_f, 13, N, 64);
    // 3) BN1+ReLU(skip) -> FB
    bn_stats<32><<<256, 256, 0, stream>>>(D, N, 64, st1);
    bn_norm_relu_bf16<32, 32><<<ceil_div((long)(N + 1) * 4, 256), 256, 0, stream>>>(
        D, N, 64, st1, st1, g2, b2, FB);
    // 4) down conv (8, 32->64): binned gather, direct writes -> Cf, fused st2
    conv_binned<32, 64, 8, false><<<ranges, 256, 0, stream>>>(
        FB, bins_d, bcnt_d, wdt, Cf, st2, M, N, 64, bcap_d);
    // 5) BN2+ReLU(Cf) -> FA [(M+1)x64]
    bn_norm_relu_bf16<64, 64><<<ceil_div((long)(M + 1) * 8, 256), 256, 0, stream>>>(
        Cf, M, 64, st2, st2, g3, b3, FA);
    // 6) conv2 (27, 64->64): binned gather incl. center -> Cf (overwrite), fused st3
    conv_binned<64, 64, 26, true><<<ranges, 256, 0, stream>>>(
        FA, bins_c, bcnt_c, w2t, Cf, st3, M, M, 64, bcap_c);
    // 7) BN3+ReLU(Cf) -> FB [(M+1)x64]
    bn_norm_relu_bf16<64, 64><<<ceil_div((long)(M + 1) * 8, 256), 256, 0, stream>>>(
        Cf, M, 64, st3, st3, g4, b4, FB);
    // 8) deconv (64->32): segments, direct writes -> D[:,32:64]; fused stats st4
    conv_sparse<64, 32, false><<<dim3(cap_u / 128, 8), 256, 0, stream>>>(
        FB, rb_up, cnt_up, wupT, D + 32, st4, cap_u, 99, M, 64);
    // 9) BN4+ReLU(D) -> FA [(N+1)x64]; low 32 ch stats = st1, high 32 = st4
    bn_norm_relu_bf16<64, 32><<<ceil_div((long)(N + 1) * 8, 256), 256, 0, stream>>>(
        D, N, 64, st1, st4, g5, b5, FA);
    // 10) conv3 (27, 64->32): center write + sparse atomics -> d_out
    conv_center<64, 32><<<ceil_div(N, 128), 256, 0, stream>>>(
        FA, w3t + 13 * 64 * 32, (float*)d_out, N, N, 32);
    conv_sparse<64, 32, true><<<dim3(cap_f / 128, 26), 256, 0, stream>>>(
        FA, rb_fine, cnt_fine, w3t, (float*)d_out, nullptr, cap_f, 13, N, 32);
}

// Round 2
// 618.216 us; speedup vs baseline: 1.2193x; 1.2193x over previous
//
#include <hip/hip_runtime.h>

// ---------------------------------------------------------------------------
// Sparse UNet forward — round 12: dense-over-taps gather conv (no rulebooks,
// no atomics on data, no conv_center, no Cf zero-fill).
//   out[m] = sum_k fpad[nbr[k][m]] @ W_k   (MFMA accumulates across taps;
//   absent neighbors gather the hot zero sentinel row).
//   - one direct write per output row + fused BN sum/sumsq
//   - MT row-tiles per wave amortize per-tap weight re-reads
// Deconv keeps the r10 segmented conv_sparse (per-row tap varies -> B-operand
// can't be shared; segments are the right form there).
// ---------------------------------------------------------------------------

#define EPS 1e-4f

typedef __attribute__((ext_vector_type(8))) short short8;   // 8 x bf16
typedef __attribute__((ext_vector_type(4))) float f32x4;

__device__ __forceinline__ unsigned short f2bf(float f) {
    union { float f; unsigned int u; } v; v.f = f;
    unsigned int r = v.u + 0x7fffu + ((v.u >> 16) & 1u);   // RNE
    return (unsigned short)(r >> 16);
}

__global__ void zero_kernel(float* p, long n) {
    long i = (long)blockIdx.x * 256 + threadIdx.x;
    if (i < n) p[i] = 0.f;
}

// Per-channel sum / sumsq -> stats[0:C], stats[C:2C] (atomic accumulate).
template <int C>
__global__ __launch_bounds__(256) void bn_stats(const float* __restrict__ x,
                                                int rows, int stride,
                                                float* __restrict__ stats) {
    const int tid = threadIdx.x;
    const int c = tid & (C - 1);
    const int g = tid / C;
    const int GR = 256 / C;
    float s = 0.f, s2 = 0.f;
    for (int r = blockIdx.x * GR + g; r < rows; r += gridDim.x * GR) {
        float v = x[(size_t)r * stride + c];
        s += v; s2 += v * v;
    }
    __shared__ float sh[2][256];
    sh[0][tid] = s; sh[1][tid] = s2;
    __syncthreads();
    for (int off = 128; off >= C; off >>= 1) {
        if (tid < off) { sh[0][tid] += sh[0][tid + off]; sh[1][tid] += sh[1][tid + off]; }
        __syncthreads();
    }
    if (tid < C) {
        atomicAdd(&stats[c], sh[0][tid]);
        atomicAdd(&stats[C + c], sh[1][tid]);
    }
}

// BN finalize + ReLU -> bf16. Output packed (rows+1) x C, sentinel row zeroed.
template <int C, int CSPLIT>
__global__ __launch_bounds__(256) void bn_norm_relu_bf16(
    const float* __restrict__ x, int rows, int stride,
    const float* __restrict__ stA, const float* __restrict__ stB,
    const float* __restrict__ gamma, const float* __restrict__ beta,
    unsigned short* __restrict__ y) {
    constexpr int TPR = C / 8;
    int gid = blockIdx.x * 256 + threadIdx.x;
    int r = gid / TPR, t = gid % TPR;
    if (r > rows) return;
    short8 o8;
    if (r == rows) {
        for (int j = 0; j < 8; ++j) o8[j] = 0;
    } else {
        const float inv_n = 1.0f / (float)rows;
        const float* xr = x + (size_t)r * stride + t * 8;
        float4 v0 = *(const float4*)(xr);
        float4 v1 = *(const float4*)(xr + 4);
        float vv[8] = {v0.x, v0.y, v0.z, v0.w, v1.x, v1.y, v1.z, v1.w};
#pragma unroll
        for (int j = 0; j < 8; ++j) {
            int c = t * 8 + j;
            const float* st = (c < CSPLIT) ? stA : stB;
            int cc = (c < CSPLIT) ? c : c - CSPLIT;
            int cs = (c < CSPLIT) ? CSPLIT : (C - CSPLIT);
            float mu = st[cc] * inv_n;
            float var = st[cs + cc] * inv_n - mu * mu;
            float sc = gamma[c] * rsqrtf(var + EPS);
            float shf = beta[c] - mu * sc;
            float ov = fmaxf(0.f, fmaf(vv[j], sc, shf));
            o8[j] = (short)f2bf(ov);
        }
    }
    *(short8*)(y + (size_t)r * C + t * 8) = o8;
}

// One dispatch: all 5 weight transposes/casts f32 [K][CIN][COUT] -> bf16
// [K][COUT][CIN].
__device__ __forceinline__ void wt_seg(const float* W, unsigned short* WT,
                                       int id, int CIN, int COUT) {
    int r = id % (CIN * COUT);
    int t = id / (CIN * COUT);
    int co = r / CIN;
    int ci = r % CIN;
    WT[id] = f2bf(W[(size_t)t * CIN * COUT + ci * COUT + co]);
}
__global__ __launch_bounds__(256) void wt_transpose_all(
    const float* w1, const float* wd, const float* w2, const float* w3,
    const float* wu, unsigned short* o1, unsigned short* od,
    unsigned short* o2, unsigned short* o3, unsigned short* ou) {
    int id = blockIdx.x * 256 + threadIdx.x;
    // segment sizes: 27648, 16384, 110592, 55296, 16384 (total 226304)
    if (id < 27648) { wt_seg(w1, o1, id, 32, 32); return; }
    id -= 27648;
    if (id < 16384) { wt_seg(wd, od, id, 32, 64); return; }
    id -= 16384;
    if (id < 110592) { wt_seg(w2, o2, id, 64, 64); return; }
    id -= 110592;
    if (id < 55296) { wt_seg(w3, o3, id, 64, 32); return; }
    id -= 55296;
    if (id < 16384) { wt_seg(wu, ou, id, 64, 32); return; }
}

// Deconv segment builder (per up_k segment, compacted (fine_row, coarse_row)).
__global__ __launch_bounds__(256) void build_rb_up(
    const int* __restrict__ up_cidx, const int* __restrict__ up_k,
    int rows, int cap, int2* __restrict__ rb, int* __restrict__ cnt) {
    const int s = blockIdx.y;
    const int lane = threadIdx.x & 63;
    const int wave = threadIdx.x >> 6;
    const long wbase = (long)blockIdx.x * 1024 + wave * 256;

    unsigned long long masks[4];
    int cs[4], ok[4], tot[4], wtotal = 0;
#pragma unroll
    for (int c = 0; c < 4; ++c) {
        long i = wbase + c * 64 + lane;
        int seg = (i < rows) ? up_k[i] : -1;
        cs[c] = (i < rows) ? up_cidx[i] : 0;
        ok[c] = (seg == s);
        masks[c] = __ballot(ok[c]);
        tot[c] = __popcll(masks[c]);
        wtotal += tot[c];
    }
    __shared__ int sh[5];
    if (lane == 0) sh[wave] = wtotal;
    __syncthreads();
    if (threadIdx.x == 0) {
        int t = sh[0] + sh[1] + sh[2] + sh[3];
        sh[4] = t ? atomicAdd(&cnt[s * 32], t) : 0;
    }
    __syncthreads();
    int base = sh[4];
    for (int w = 0; w < wave; ++w) base += sh[w];
#pragma unroll
    for (int c = 0; c < 4; ++c) {
        if (ok[c]) {
            int rank = __popcll(masks[c] & ((1ull << lane) - 1ull));
            int j = base + rank;
            if (j < cap)
                rb[(size_t)s * cap + j] = make_int2((int)(wbase + c * 64 + lane), cs[c]);
        }
        base += tot[c];
    }
}

// ---- conv kernels ----------------------------------------------------------

// Dense-over-taps gather conv: each wave owns MT 16-row output tiles and
// accumulates all NTAP taps in MFMA accumulators (absent neighbor -> sentinel
// zero row). One direct write per row; optional fused BN stats.
template <int CIN, int COT, int NTAP, int MT>
__global__ __launch_bounds__(256) void conv_dense(
    const unsigned short* __restrict__ fpad,
    const int* __restrict__ nbr,
    const unsigned short* __restrict__ WT,
    float* __restrict__ out,
    float* __restrict__ stats,
    int rows, int P, int out_stride) {
    constexpr int N_SUB = COT / 16;
    constexpr int K_SUB = CIN / 32;
    const int tid = threadIdx.x;
    const int wave = tid >> 6;
    const int lane = tid & 63;
    const int q = lane >> 4;
    const int l15 = lane & 15;
    const int m0 = blockIdx.x * (64 * MT) + wave * (16 * MT);

    int mrow[MT], mok[MT];
#pragma unroll
    for (int mt = 0; mt < MT; ++mt) {
        int m = m0 + mt * 16 + l15;
        mok[mt] = (m < rows);
        mrow[mt] = mok[mt] ? m : 0;
    }

    f32x4 acc[MT][N_SUB];
#pragma unroll
    for (int mt = 0; mt < MT; ++mt)
#pragma unroll
        for (int nt = 0; nt < N_SUB; ++nt) acc[mt][nt] = (f32x4){0.f, 0.f, 0.f, 0.f};

    // tap-0 index prefetch; each iteration prefetches the next tap's indices
    // (independent of the MFMA accumulator chain).
    int idx[MT];
#pragma unroll
    for (int mt = 0; mt < MT; ++mt)
        idx[mt] = mok[mt] ? nbr[mrow[mt]] : P;

    for (int k = 0; k < NTAP; ++k) {
        int nxt[MT];
#pragma unroll
        for (int mt = 0; mt < MT; ++mt)
            nxt[mt] = (k + 1 < NTAP && mok[mt]) ? nbr[(size_t)(k + 1) * rows + mrow[mt]] : P;

        const unsigned short* Wk = WT + (size_t)k * COT * CIN;
        short8 b[N_SUB][K_SUB];
#pragma unroll
        for (int nt = 0; nt < N_SUB; ++nt)
#pragma unroll
            for (int kf = 0; kf < K_SUB; ++kf)
                b[nt][kf] = *(const short8*)(Wk + (size_t)(nt * 16 + l15) * CIN + kf * 32 + q * 8);

        short8 a[MT][K_SUB];
#pragma unroll
        for (int mt = 0; mt < MT; ++mt) {
            const unsigned short* ap = fpad + (size_t)idx[mt] * CIN + q * 8;
#pragma unroll
            for (int kf = 0; kf < K_SUB; ++kf)
                a[mt][kf] = *(const short8*)(ap + kf * 32);
        }
#pragma unroll
        for (int mt = 0; mt < MT; ++mt)
#pragma unroll
            for (int nt = 0; nt < N_SUB; ++nt)
#pragma unroll
                for (int kf = 0; kf < K_SUB; ++kf)
                    acc[mt][nt] = __builtin_amdgcn_mfma_f32_16x16x32_bf16(
                        a[mt][kf], b[nt][kf], acc[mt][nt], 0, 0, 0);
#pragma unroll
        for (int mt = 0; mt < MT; ++mt) idx[mt] = nxt[mt];
    }

    // Direct write, once per output row.
#pragma unroll
    for (int mt = 0; mt < MT; ++mt)
#pragma unroll
        for (int i = 0; i < 4; ++i) {
            int row = m0 + mt * 16 + q * 4 + i;
            if (row < rows) {
#pragma unroll
                for (int nt = 0; nt < N_SUB; ++nt)
                    out[(size_t)row * out_stride + nt * 16 + l15] = acc[mt][nt][i];
            }
        }

    // Fused BN stats (final values; OOB lanes hold acc==0).
    if (stats) {
        __shared__ float ssum[COT], ssq[COT];
        for (int i = tid; i < 2 * COT; i += 256)
            (i < COT ? ssum[i] : ssq[i - COT]) = 0.f;
        __syncthreads();
#pragma unroll
        for (int nt = 0; nt < N_SUB; ++nt) {
            float s = 0.f, s2 = 0.f;
#pragma unroll
            for (int mt = 0; mt < MT; ++mt)
#pragma unroll
                for (int i = 0; i < 4; ++i) {
                    float v = acc[mt][nt][i];
                    s += v; s2 += v * v;
                }
            s += __shfl_xor(s, 16);  s += __shfl_xor(s, 32);
            s2 += __shfl_xor(s2, 16); s2 += __shfl_xor(s2, 32);
            if (q == 0) {
                atomicAdd(&ssum[nt * 16 + l15], s);
                atomicAdd(&ssq[nt * 16 + l15], s2);
            }
        }
        __syncthreads();
        if (tid < COT) {
            atomicAdd(&stats[tid], ssum[tid]);
            atomicAdd(&stats[COT + tid], ssq[tid]);
        }
    }
}

// Segmented gather-GEMM over compacted rulebook tiles (deconv only: per-row
// tap varies, so segments-by-tap with direct writes is the right form).
template <int CIN, int COT, bool ATOMIC>
__global__ __launch_bounds__(256) void conv_sparse(
    const unsigned short* __restrict__ fpad,
    const int2* __restrict__ rb,
    const int* __restrict__ cnt,
    const unsigned short* __restrict__ WT,
    float* __restrict__ out,
    float* __restrict__ stats,
    int cap, int kskip, int P, int out_stride) {
    constexpr int N_SUB = COT / 16;
    constexpr int K_SUB = CIN / 32;
    const int tap = blockIdx.y;
    int n = cnt[tap * 32];
    n = n < cap ? n : cap;
    const int nbx = gridDim.x;
    const int step = (nbx >> 3) | 1;
    const int px = (int)((blockIdx.x + (unsigned)tap * step) % (unsigned)nbx);
    const int base0 = px * 128;
    if (base0 >= n) return;
    const int k = tap + (tap >= kskip ? 1 : 0);
    const int tid = threadIdx.x;
    const int wave = tid >> 6;
    const int lane = tid & 63;
    const int q = lane >> 4;
    const int l15 = lane & 15;
    const int base = base0 + wave * 32;
    const int2* seg = rb + (size_t)tap * cap;

    f32x4 acc[2][N_SUB];
#pragma unroll
    for (int mt = 0; mt < 2; ++mt)
#pragma unroll
        for (int nt = 0; nt < N_SUB; ++nt) acc[mt][nt] = (f32x4){0.f, 0.f, 0.f, 0.f};

    short8 a[2][K_SUB], b[N_SUB][K_SUB];
#pragma unroll
    for (int mt = 0; mt < 2; ++mt) {
        int j = base + mt * 16 + l15;
        int src = (j < n) ? seg[j].y : P;
#pragma unroll
        for (int kf = 0; kf < K_SUB; ++kf)
            a[mt][kf] = *(const short8*)(fpad + (size_t)src * CIN + kf * 32 + q * 8);
    }
    const unsigned short* Wk = WT + (size_t)k * COT * CIN;
#pragma unroll
    for (int nt = 0; nt < N_SUB; ++nt)
#pragma unroll
        for (int kf = 0; kf < K_SUB; ++kf)
            b[nt][kf] = *(const short8*)(Wk + (size_t)(nt * 16 + l15) * CIN + kf * 32 + q * 8);
#pragma unroll
    for (int mt = 0; mt < 2; ++mt)
#pragma unroll
        for (int nt = 0; nt < N_SUB; ++nt)
#pragma unroll
            for (int kf = 0; kf < K_SUB; ++kf)
                acc[mt][nt] = __builtin_amdgcn_mfma_f32_16x16x32_bf16(
                    a[mt][kf], b[nt][kf], acc[mt][nt], 0, 0, 0);

#pragma unroll
    for (int mt = 0; mt < 2; ++mt)
#pragma unroll
        for (int i = 0; i < 4; ++i) {
            int j = base + mt * 16 + q * 4 + i;
            if (j < n) {
                int row = seg[j].x;
                float* o = out + (size_t)row * out_stride + l15;
#pragma unroll
                for (int nt = 0; nt < N_SUB; ++nt) {
                    if (ATOMIC) atomicAdd(o + nt * 16, acc[mt][nt][i]);
                    else        o[nt * 16] = acc[mt][nt][i];
                }
            }
        }

    // Fused BN stats (final-value writes only): OOB lanes hold acc==0.
    if (!ATOMIC && stats) {
        __shared__ float ssum[COT], ssq[COT];
        for (int i = tid; i < 2 * COT; i += 256)
            (i < COT ? ssum[i] : ssq[i - COT]) = 0.f;
        __syncthreads();
#pragma unroll
        for (int nt = 0; nt < N_SUB; ++nt) {
            float s = 0.f, s2 = 0.f;
#pragma unroll
            for (int mt = 0; mt < 2; ++mt)
#pragma unroll
                for (int i = 0; i < 4; ++i) {
                    float v = acc[mt][nt][i];
                    s += v; s2 += v * v;
                }
            s += __shfl_xor(s, 16);  s += __shfl_xor(s, 32);
            s2 += __shfl_xor(s2, 16); s2 += __shfl_xor(s2, 32);
            if (q == 0) {
                atomicAdd(&ssum[nt * 16 + l15], s);
                atomicAdd(&ssq[nt * 16 + l15], s2);
            }
        }
        __syncthreads();
        if (tid < COT) {
            atomicAdd(&stats[tid], ssum[tid]);
            atomicAdd(&stats[COT + tid], ssq[tid]);
        }
    }
}

static inline int ceil_div(long a, long b) { return (int)((a + b - 1) / b); }

extern "C" void kernel_launch(void* const* d_in, const int* in_sizes, int n_in,
                              void* d_out, int out_size, void* d_ws, size_t ws_size,
                              hipStream_t stream) {
    const float* feat   = (const float*)d_in[0];
    const float* w_sub1 = (const float*)d_in[1];
    const float* w_down = (const float*)d_in[2];
    const float* w_sub2 = (const float*)d_in[3];
    const float* w_up   = (const float*)d_in[4];
    const float* w_sub3 = (const float*)d_in[5];
    const float* g1 = (const float*)d_in[6],  *b1 = (const float*)d_in[7];
    const float* g2 = (const float*)d_in[8],  *b2 = (const float*)d_in[9];
    const float* g3 = (const float*)d_in[10], *b3 = (const float*)d_in[11];
    const float* g4 = (const float*)d_in[12], *b4 = (const float*)d_in[13];
    const float* g5 = (const float*)d_in[14], *b5 = (const float*)d_in[15];
    const int* nbr_fine   = (const int*)d_in[16];
    const int* nbr_coarse = (const int*)d_in[17];
    const int* down_idx   = (const int*)d_in[18];
    const int* up_cidx    = (const int*)d_in[19];
    const int* up_k       = (const int*)d_in[20];

    const int N = in_sizes[0] / 32;
    const int M = in_sizes[17] / 27;
    const size_t maxr = (size_t)((N > M ? N : M) + 1);

    const int cap_u = 32768;     // up segments (~25.6k expected)

    char* ws = (char*)d_ws;
    size_t off = 0;
    auto alloc = [&](size_t bytes) { void* p = ws + off; off += (bytes + 255) & ~(size_t)255; return p; };
    float* stats = (float*)alloc(768 * sizeof(float));
    int*   cnts  = (int*)alloc(1024 * sizeof(int));              // up: 8 taps * 32 stride
    const size_t zero_words = off / 4;                            // stats..cnts contiguous
    float* D  = (float*)alloc((size_t)N * 64 * sizeof(float));    // concat buf [skip|up]
    float* Cf = (float*)alloc((size_t)M * 64 * sizeof(float));    // coarse f32 temp
    unsigned short* FA = (unsigned short*)alloc(maxr * 64 * 2);
    unsigned short* FB = (unsigned short*)alloc(maxr * 64 * 2);
    int2* rb_up = (int2*)alloc((size_t)8 * cap_u * sizeof(int2));
    unsigned short* w1t = (unsigned short*)alloc(27 * 32 * 32 * 2);
    unsigned short* wdt = (unsigned short*)alloc(8 * 32 * 64 * 2);
    unsigned short* w2t = (unsigned short*)alloc(27 * 64 * 64 * 2);
    unsigned short* w3t = (unsigned short*)alloc(27 * 64 * 32 * 2);
    unsigned short* wupT = (unsigned short*)alloc(8 * 64 * 32 * 2);

    float* st0 = stats + 0 * 128;   // feat (32 ch)
    float* st1 = stats + 1 * 128;   // conv1 out (32 ch, fused)
    float* st2 = stats + 2 * 128;   // down out (64 ch, fused)
    float* st3 = stats + 3 * 128;   // conv2 out (64 ch, fused)
    float* st4 = stats + 4 * 128;   // deconv out (32 ch, fused)
    int* cnt_up = cnts;

    // ---- setup ----
    zero_kernel<<<ceil_div((long)zero_words, 256), 256, 0, stream>>>(stats, (long)zero_words);
    wt_transpose_all<<<ceil_div(226304, 256), 256, 0, stream>>>(
        w_sub1, w_down, w_sub2, w_sub3, w_up, w1t, wdt, w2t, w3t, wupT);
    build_rb_up<<<dim3(ceil_div(N, 1024), 8), 256, 0, stream>>>(
        up_cidx, up_k, N, cap_u, rb_up, cnt_up);

    // 1) BN0+ReLU(feat) -> FA [(N+1)x32 bf16]
    bn_stats<32><<<256, 256, 0, stream>>>(feat, N, 32, st0);
    bn_norm_relu_bf16<32, 32><<<ceil_div((long)(N + 1) * 4, 256), 256, 0, stream>>>(
        feat, N, 32, st0, st0, g1, b1, FA);
    // 2) conv1 (27, 32->32): dense-over-taps gather -> D[:,0:32], fused st1
    conv_dense<32, 32, 27, 2><<<ceil_div(N, 128), 256, 0, stream>>>(
        FA, nbr_fine, w1t, D, st1, N, N, 64);
    // 3) BN1+ReLU(skip) -> FB
    bn_norm_relu_bf16<32, 32><<<ceil_div((long)(N + 1) * 4, 256), 256, 0, stream>>>(
        D, N, 64, st1, st1, g2, b2, FB);
    // 4) down conv (8, 32->64): dense-over-taps gather -> Cf, fused st2
    conv_dense<32, 64, 8, 4><<<ceil_div(M, 256), 256, 0, stream>>>(
        FB, down_idx, wdt, Cf, st2, M, N, 64);
    // 5) BN2+ReLU(Cf) -> FA [(M+1)x64]
    bn_norm_relu_bf16<64, 64><<<ceil_div((long)(M + 1) * 8, 256), 256, 0, stream>>>(
        Cf, M, 64, st2, st2, g3, b3, FA);
    // 6) conv2 (27, 64->64): dense-over-taps gather -> Cf (overwrite), fused st3
    conv_dense<64, 64, 27, 4><<<ceil_div(M, 256), 256, 0, stream>>>(
        FA, nbr_coarse, w2t, Cf, st3, M, M, 64);
    // 7) BN3+ReLU(Cf) -> FB [(M+1)x64]
    bn_norm_relu_bf16<64, 64><<<ceil_div((long)(M + 1) * 8, 256), 256, 0, stream>>>(
        Cf, M, 64, st3, st3, g4, b4, FB);
    // 8) deconv (64->32): segments, direct writes -> D[:,32:64]; fused stats st4
    conv_sparse<64, 32, false><<<dim3(cap_u / 128, 8), 256, 0, stream>>>(
        FB, rb_up, cnt_up, wupT, D + 32, st4, cap_u, 99, M, 64);
    // 9) BN4+ReLU(D) -> FA [(N+1)x64]; low 32 ch stats = st1, high 32 = st4
    bn_norm_relu_bf16<64, 32><<<ceil_div((long)(N + 1) * 8, 256), 256, 0, stream>>>(
        D, N, 64, st1, st4, g5, b5, FA);
    // 10) conv3 (27, 64->32): dense-over-taps gather -> d_out
    conv_dense<64, 32, 27, 4><<<ceil_div(N, 256), 256, 0, stream>>>(
        FA, nbr_fine, w3t, (float*)d_out, nullptr, N, N, 32);
}